// Round 10
// baseline (244.581 us; speedup 1.0000x reference)
//
#include <hip/hip_runtime.h>

#define N_NODES 100000
#define N_EDGES 1600000
#define IN_DIM 128
#define H1_DIM 64
#define H2_DIM 32
#define OUT_DIM 16

#define NPB 64                       // src-nodes per bucket
#define KB 1563                      // ceil(N_NODES / NPB)
#define OFFW (KB + 1)                // off-table row width (with sentinel)
#define NCH 256                      // edge chunks (private regions)
#define CH_E (N_EDGES / NCH)         // 6250 edges per chunk (exact)
#define CAP2 1536                    // per-bucket record cap (mean 1024, +16 sigma)
#define NGB 782                      // ceil(N_NODES / 128) gemmy blocks

typedef __attribute__((ext_vector_type(8))) short short8;
typedef __attribute__((ext_vector_type(4))) float f32x4;

// ---------------- helpers ----------------
__device__ inline unsigned short f2b(float v) {   // RNE f32 -> bf16
    unsigned u = __float_as_uint(v);
    u += 0x7FFF + ((u >> 16) & 1);
    return (unsigned short)(u >> 16);
}
__device__ inline short f2bs(float v) { return (short)f2b(v); }
__device__ inline unsigned f32_to_key(float v) {
    unsigned u = __float_as_uint(v);
    return (v >= 0.f) ? (u | 0x80000000u) : ~u;
}
__device__ __forceinline__ void acc8(float* a, uint4 v) {
    a[0] += __uint_as_float(v.x << 16);
    a[1] += __uint_as_float(v.x & 0xFFFF0000u);
    a[2] += __uint_as_float(v.y << 16);
    a[3] += __uint_as_float(v.y & 0xFFFF0000u);
    a[4] += __uint_as_float(v.z << 16);
    a[5] += __uint_as_float(v.z & 0xFFFF0000u);
    a[6] += __uint_as_float(v.w << 16);
    a[7] += __uint_as_float(v.w & 0xFFFF0000u);
}

// ---------------- bin chunk: 512 threads ----------------
__device__ __forceinline__ void bin_chunk(const int* __restrict__ src,
                                          const int* __restrict__ dst,
                                          unsigned* __restrict__ off,
                                          unsigned* __restrict__ grec, int c) {
    __shared__ int hist[2048];
    __shared__ int part[512];
    __shared__ int cur[2048];
    int t = threadIdx.x;
    int e0 = c * CH_E;
    for (int i = t; i < 2048; i += 512) hist[i] = 0;
    __syncthreads();
    for (int e = t; e < CH_E; e += 512) atomicAdd(&hist[src[e0 + e] >> 6], 1);
    __syncthreads();
    int h0 = hist[4 * t], h1 = hist[4 * t + 1], h2 = hist[4 * t + 2], h3 = hist[4 * t + 3];
    int tot = h0 + h1 + h2 + h3;
    part[t] = tot;
    __syncthreads();
    for (int o = 1; o < 512; o <<= 1) {
        int a = (t >= o) ? part[t - o] : 0;
        __syncthreads();
        part[t] += a;
        __syncthreads();
    }
    int gb = part[t] - tot;
    int o0 = gb, o1 = gb + h0, o2 = o1 + h1, o3 = o2 + h2;
    int b4 = 4 * t;
    cur[b4] = o0; cur[b4 + 1] = o1; cur[b4 + 2] = o2; cur[b4 + 3] = o3;
    if (b4 + 0 < KB) off[(size_t)c * OFFW + b4 + 0] = o0;
    if (b4 + 1 < KB) off[(size_t)c * OFFW + b4 + 1] = o1;
    if (b4 + 2 < KB) off[(size_t)c * OFFW + b4 + 2] = o2;
    if (b4 + 3 < KB) off[(size_t)c * OFFW + b4 + 3] = o3;
    if (t == 0) off[(size_t)c * OFFW + KB] = CH_E;   // sentinel
    __syncthreads();
    for (int e = t; e < CH_E; e += 512) {
        int s = src[e0 + e];
        int d = dst[e0 + e];
        int p = atomicAdd(&cur[s >> 6], 1);
        grec[(size_t)e0 + p] = ((unsigned)(s & 63) << 17) | (unsigned)d;
    }
}

// ---------------- K_A: all 256 bin chunks  ||  gemmy with inline Wc ----------
__global__ __launch_bounds__(512) void ka_kernel(const int* __restrict__ src,
                                                 const int* __restrict__ dst,
                                                 unsigned* __restrict__ off,
                                                 unsigned* __restrict__ grec,
                                                 const float* __restrict__ x,
                                                 const float* __restrict__ W1,
                                                 const float* __restrict__ W2,
                                                 unsigned short* __restrict__ yb) {
    __shared__ unsigned short wl[H2_DIM * 136];   // padded stride (272B)
    if (blockIdx.x < NCH) {
        bin_chunk(src, dst, off, grec, blockIdx.x);
        return;
    }
    int gb = blockIdx.x - NCH;
    int t = threadIdx.x;
    // inline Wc = bf16(W2@W1): 8 outputs/thread, 64 FMAs each (~0.25 us/block)
    for (int idx = t; idx < H2_DIM * IN_DIM; idx += 512) {
        int j = idx >> 7, f = idx & 127;
        float acc = 0.f;
        for (int k = 0; k < H1_DIM; ++k)
            acc += W2[j * H1_DIM + k] * W1[k * IN_DIM + f];
        wl[j * 136 + f] = f2b(acc);
    }
    __syncthreads();
    int w = t >> 6, l = t & 63;
    int row = l & 15, kg = l >> 4;          // kg in 0..3
    int base = gb * 128 + w * 16;
    int node = base + row;
    int nclamp = (node < N_NODES) ? node : (N_NODES - 1);
    const float* xp = x + (size_t)nclamp * IN_DIM + kg * 8;
    const unsigned short* b0p = wl + row * 136 + kg * 8;
    const unsigned short* b1p = wl + (16 + row) * 136 + kg * 8;
    f32x4 acc0 = {0.f, 0.f, 0.f, 0.f}, acc1 = {0.f, 0.f, 0.f, 0.f};
#pragma unroll
    for (int kk = 0; kk < 4; ++kk) {
        float4 xa = *(const float4*)(xp + kk * 32);
        float4 xb = *(const float4*)(xp + kk * 32 + 4);
        short8 a;
        a[0] = f2bs(xa.x); a[1] = f2bs(xa.y); a[2] = f2bs(xa.z); a[3] = f2bs(xa.w);
        a[4] = f2bs(xb.x); a[5] = f2bs(xb.y); a[6] = f2bs(xb.z); a[7] = f2bs(xb.w);
        short8 b0 = *(const short8*)(b0p + kk * 32);
        short8 b1 = *(const short8*)(b1p + kk * 32);
        acc0 = __builtin_amdgcn_mfma_f32_16x16x32_bf16(a, b0, acc0, 0, 0, 0);
        acc1 = __builtin_amdgcn_mfma_f32_16x16x32_bf16(a, b1, acc1, 0, 0, 0);
    }
#pragma unroll
    for (int r = 0; r < 4; ++r) {
        int n2 = base + kg * 4 + r;
        if (n2 < N_NODES) {
            yb[(size_t)n2 * H2_DIM + row]      = f2b(acc0[r]);
            yb[(size_t)n2 * H2_DIM + 16 + row] = f2b(acc1[r]);
        }
    }
}

// ---------------- agg: 16-lane groups, 2x uint4 in flight (proven 24-28 VGPR) -
// Lane in group: chunk=L&3 (features 8c..8c+7, 16B), subset=L>>2 (record e+subset).
// Per node-iter: 8 records (2 quads in flight); shfl_xor(4,8) folds subsets.
// ROUND 2 also runs the last-block final epilogue (pooled @ Wf^T + bf).
template <int ROUND>
__global__ __launch_bounds__(256) void agg_kernel(const unsigned short* __restrict__ in,
                                                  const unsigned* __restrict__ off,
                                                  const unsigned* __restrict__ grec,
                                                  unsigned* __restrict__ grec2,
                                                  unsigned* __restrict__ noff,
                                                  unsigned short* __restrict__ z1b,
                                                  const float* __restrict__ W2,
                                                  const float* __restrict__ b1,
                                                  const float* __restrict__ b2,
                                                  const float* __restrict__ Wf,
                                                  const float* __restrict__ bfv,
                                                  unsigned* __restrict__ pk,
                                                  unsigned* __restrict__ done,
                                                  float* __restrict__ out) {
    __shared__ int len[NCH], pos[NCH], sst[NCH];
    __shared__ int shist[64], scur2[64];
    __shared__ int sscan[65];
    __shared__ unsigned rbuf[CAP2];
    __shared__ unsigned sbuf[CAP2];
    __shared__ float smq[16][4][8];
    __shared__ float scv[32], sb2v[32];
    __shared__ int s_cnt;
    __shared__ unsigned s_ticket;
    int t = threadIdx.x;
    int b = blockIdx.x;
    int gid = t >> 4;              // 16 groups of 16 lanes
    int L = t & 15;
    int chunk = L & 3, subset = L >> 2;

    if (ROUND == 1) {
        {   // region table + scan (NCH == blockDim)
            unsigned o0 = off[(size_t)t * OFFW + b];
            unsigned o1 = off[(size_t)t * OFFW + b + 1];
            sst[t] = (int)o0;
            len[t] = (int)(o1 - o0);
            pos[t] = (int)(o1 - o0);
        }
        __syncthreads();
        for (int o = 1; o < NCH; o <<= 1) {
            int a = (t >= o) ? pos[t - o] : 0;
            __syncthreads();
            pos[t] += a;
            __syncthreads();
        }
        pos[t] -= len[t];              // exclusive
        if (t == NCH - 1) s_cnt = min(pos[t] + len[t], CAP2);
        __syncthreads();
        for (int c = gid; c < NCH; c += 16) {
            int Ln = len[c], P = pos[c], S = sst[c];
            for (int k = L; k < Ln; k += 16) {
                int q = P + k;
                if (q < CAP2) rbuf[q] = grec[(size_t)c * CH_E + S + k];
            }
        }
        if (t < 64) shist[t] = 0;
        __syncthreads();
        int cnt = s_cnt;
        for (int i = t; i < cnt; i += 256) atomicAdd(&shist[rbuf[i] >> 17], 1);
        __syncthreads();
        if (t < 64) scur2[t] = shist[t];
        __syncthreads();
        for (int o = 1; o < 64; o <<= 1) {
            int a = (t < 64 && t >= o) ? scur2[t - o] : 0;
            __syncthreads();
            if (t < 64) scur2[t] += a;
            __syncthreads();
        }
        if (t < 64) sscan[t] = scur2[t] - shist[t];
        if (t == 63) sscan[64] = scur2[63];
        __syncthreads();
        if (t < 64) scur2[t] = sscan[t];
        __syncthreads();
        for (int i = t; i < cnt; i += 256) {
            unsigned r = rbuf[i];
            int p = atomicAdd(&scur2[r >> 17], 1);
            if (p < CAP2) sbuf[p] = r;
        }
        __syncthreads();
        for (int i = t; i < cnt; i += 256) grec2[(size_t)b * CAP2 + i] = sbuf[i];
        if (t < 65) noff[(size_t)b * 65 + t] = (unsigned)sscan[t];
    } else {
        if (t < 65) sscan[t] = (int)noff[(size_t)b * 65 + t];
        __syncthreads();
        int cnt = sscan[64];
        for (int i = t; i < cnt; i += 256) sbuf[i] = grec2[(size_t)b * CAP2 + i];
        if (t < 32) {                  // inline cvec = W2 @ b1
            float s = 0.f;
            for (int k = 0; k < H1_DIM; ++k) s += W2[t * H1_DIM + k] * b1[k];
            scv[t] = s;
            sb2v[t] = b2[t];
        }
    }
    __syncthreads();

    float cfv[8], bbv[8], m[8];
    if (ROUND == 2) {
#pragma unroll
        for (int j = 0; j < 8; ++j) {
            cfv[j] = scv[chunk * 8 + j];
            bbv[j] = sb2v[chunk * 8 + j];
            m[j] = -3.402823466e+38f;
        }
    }

    for (int sl = gid; sl < NPB; sl += 16) {
        int r0 = sscan[sl], r1 = sscan[sl + 1];
        float a[8] = {0.f, 0.f, 0.f, 0.f, 0.f, 0.f, 0.f, 0.f};
        float aa[8] = {0.f, 0.f, 0.f, 0.f, 0.f, 0.f, 0.f, 0.f};
        for (int e = r0; e < r1; e += 8) {
            int eA = e + subset, eB = e + 4 + subset;
            if (eA < r1) {
                unsigned rc = sbuf[eA];
                uint4 v = *(const uint4*)(in + (size_t)(rc & 0x1FFFFu) * H2_DIM + chunk * 8);
                acc8(a, v);
            }
            if (eB < r1) {
                unsigned rc = sbuf[eB];
                uint4 v = *(const uint4*)(in + (size_t)(rc & 0x1FFFFu) * H2_DIM + chunk * 8);
                acc8(aa, v);
            }
        }
#pragma unroll
        for (int j = 0; j < 8; ++j) {
            float s = a[j] + aa[j];
            s += __shfl_xor(s, 4);
            s += __shfl_xor(s, 8);
            a[j] = s;
        }
        int node = b * NPB + sl;
        if (node < N_NODES) {
            if (ROUND == 1) {
                if (subset == 0) {
                    uint4 o;
                    o.x = (unsigned)f2b(a[0]) | ((unsigned)f2b(a[1]) << 16);
                    o.y = (unsigned)f2b(a[2]) | ((unsigned)f2b(a[3]) << 16);
                    o.z = (unsigned)f2b(a[4]) | ((unsigned)f2b(a[5]) << 16);
                    o.w = (unsigned)f2b(a[6]) | ((unsigned)f2b(a[7]) << 16);
                    *(uint4*)(z1b + (size_t)node * H2_DIM + chunk * 8) = o;
                }
            } else {
                float dg = (float)(r1 - r0);
#pragma unroll
                for (int j = 0; j < 8; ++j)
                    m[j] = fmaxf(m[j], a[j] + dg * cfv[j] + bbv[j]);
            }
        }
    }
    if (ROUND == 2) {
        if (subset == 0) {
#pragma unroll
            for (int j = 0; j < 8; ++j) smq[gid][chunk][j] = m[j];
        }
        __syncthreads();
        if (t < 32) {                  // feature f == t
            int c = t >> 3, j = t & 7;
            float mm = smq[0][c][j];
#pragma unroll
            for (int k = 1; k < 16; ++k) mm = fmaxf(mm, smq[k][c][j]);
            atomicMax(&pk[t], f32_to_key(mm));
        }
        // ---- last-block final epilogue: out = pooled @ Wf^T + bf ----
        __threadfence();
        __syncthreads();
        if (t == 0) s_ticket = atomicAdd(done, 1u);
        __syncthreads();
        if (s_ticket == KB - 1) {
            if (t < 32) {
                unsigned k = atomicMax(&pk[t], 0u);   // coherent read-back
                unsigned u = (k & 0x80000000u) ? (k & 0x7FFFFFFFu) : ~k;
                scv[t] = __uint_as_float(u);          // pooled
            }
            __syncthreads();
            if (t < OUT_DIM) {
                float acc = bfv[t];
                for (int j = 0; j < H2_DIM; ++j)
                    acc += Wf[t * H2_DIM + j] * scv[j];
                out[t] = acc;
            }
        }
    }
}

extern "C" void kernel_launch(void* const* d_in, const int* in_sizes, int n_in,
                              void* d_out, int out_size, void* d_ws, size_t ws_size,
                              hipStream_t stream) {
    const float* x  = (const float*)d_in[0];
    const int*   ei = (const int*)d_in[1];           // [2, E]: row0 = src, row1 = dst
    const float* W1 = (const float*)d_in[2];
    const float* b1 = (const float*)d_in[3];
    const float* W2 = (const float*)d_in[4];
    const float* b2 = (const float*)d_in[5];
    const float* Wf = (const float*)d_in[6];
    const float* bf = (const float*)d_in[7];
    float* out = (float*)d_out;

    const int* src = ei;
    const int* dst = ei + N_EDGES;

    // workspace carve-up (~32 MB)
    unsigned short* yb  = (unsigned short*)d_ws;                 // N*32 bf16
    unsigned short* z1b = yb + (size_t)N_NODES * H2_DIM;         // N*32 bf16
    unsigned* pk    = (unsigned*)(z1b + (size_t)N_NODES * H2_DIM); // 32
    unsigned* done  = pk + H2_DIM;                               // 1
    unsigned* off   = done + 1;                                  // NCH*OFFW
    unsigned* grec  = off + (size_t)NCH * OFFW;                  // N_EDGES
    unsigned* grec2 = grec + N_EDGES;                            // KB*CAP2
    unsigned* noff  = grec2 + (size_t)KB * CAP2;                 // KB*65

    hipMemsetAsync(pk, 0, (H2_DIM + 1) * sizeof(unsigned), stream);

    ka_kernel<<<NCH + NGB, 512, 0, stream>>>(src, dst, off, grec, x, W1, W2, yb);

    agg_kernel<1><<<KB, 256, 0, stream>>>(yb, off, grec, grec2, noff, z1b,
                                          nullptr, nullptr, nullptr,
                                          nullptr, nullptr, pk, done, nullptr);
    agg_kernel<2><<<KB, 256, 0, stream>>>(z1b, off, grec, grec2, noff, nullptr,
                                          W2, b1, b2, Wf, bf, pk, done, out);
}

// Round 11
// 125.407 us; speedup vs baseline: 1.9503x; 1.9503x over previous
//
#include <hip/hip_runtime.h>

#define N_NODES 100000
#define N_EDGES 1600000
#define IN_DIM 128
#define H1_DIM 64
#define H2_DIM 32
#define OUT_DIM 16

#define NPB 64                       // src-nodes per bucket
#define KB 1563                      // ceil(N_NODES / NPB)
#define OFFW (KB + 1)                // off-table row width (with sentinel)
#define NCH 256                      // edge chunks (private regions)
#define CH_E (N_EDGES / NCH)         // 6250 edges per chunk (exact)
#define CAP2 1536                    // per-bucket record cap (mean 1024, +16 sigma)
#define NBIN1 64                     // bin chunks done in K1 (with prep)
#define NBIN2 (NCH - NBIN1)          // bin chunks done in K2 (with gemmy)
#define NGB 782                      // ceil(N_NODES / 128) gemmy blocks

typedef __attribute__((ext_vector_type(8))) short short8;
typedef __attribute__((ext_vector_type(4))) float f32x4;

// ---------------- helpers ----------------
__device__ inline unsigned short f2b(float v) {   // RNE f32 -> bf16
    unsigned u = __float_as_uint(v);
    u += 0x7FFF + ((u >> 16) & 1);
    return (unsigned short)(u >> 16);
}
__device__ inline short f2bs(float v) { return (short)f2b(v); }
__device__ inline unsigned f32_to_key(float v) {
    unsigned u = __float_as_uint(v);
    return (v >= 0.f) ? (u | 0x80000000u) : ~u;
}
__device__ __forceinline__ void acc8(float* a, uint4 v) {
    a[0] += __uint_as_float(v.x << 16);
    a[1] += __uint_as_float(v.x & 0xFFFF0000u);
    a[2] += __uint_as_float(v.y << 16);
    a[3] += __uint_as_float(v.y & 0xFFFF0000u);
    a[4] += __uint_as_float(v.z << 16);
    a[5] += __uint_as_float(v.z & 0xFFFF0000u);
    a[6] += __uint_as_float(v.w << 16);
    a[7] += __uint_as_float(v.w & 0xFFFF0000u);
}

// ---------------- bin chunk (shared by K1/K2): 512 threads ----------------
__device__ __forceinline__ void bin_chunk(const int* __restrict__ src,
                                          const int* __restrict__ dst,
                                          unsigned* __restrict__ off,
                                          unsigned* __restrict__ grec, int c) {
    __shared__ int hist[2048];
    __shared__ int part[512];
    __shared__ int cur[2048];
    int t = threadIdx.x;
    int e0 = c * CH_E;
    for (int i = t; i < 2048; i += 512) hist[i] = 0;
    __syncthreads();
    for (int e = t; e < CH_E; e += 512) atomicAdd(&hist[src[e0 + e] >> 6], 1);
    __syncthreads();
    int h0 = hist[4 * t], h1 = hist[4 * t + 1], h2 = hist[4 * t + 2], h3 = hist[4 * t + 3];
    int tot = h0 + h1 + h2 + h3;
    part[t] = tot;
    __syncthreads();
    for (int o = 1; o < 512; o <<= 1) {
        int a = (t >= o) ? part[t - o] : 0;
        __syncthreads();
        part[t] += a;
        __syncthreads();
    }
    int gb = part[t] - tot;
    int o0 = gb, o1 = gb + h0, o2 = o1 + h1, o3 = o2 + h2;
    int b4 = 4 * t;
    cur[b4] = o0; cur[b4 + 1] = o1; cur[b4 + 2] = o2; cur[b4 + 3] = o3;
    if (b4 + 0 < KB) off[(size_t)c * OFFW + b4 + 0] = o0;
    if (b4 + 1 < KB) off[(size_t)c * OFFW + b4 + 1] = o1;
    if (b4 + 2 < KB) off[(size_t)c * OFFW + b4 + 2] = o2;
    if (b4 + 3 < KB) off[(size_t)c * OFFW + b4 + 3] = o3;
    if (t == 0) off[(size_t)c * OFFW + KB] = CH_E;   // sentinel
    __syncthreads();
    for (int e = t; e < CH_E; e += 512) {
        int s = src[e0 + e];
        int d = dst[e0 + e];
        int p = atomicAdd(&cur[s >> 6], 1);
        grec[(size_t)e0 + p] = ((unsigned)(s & 63) << 17) | (unsigned)d;
    }
}

// ---------------- K1: bin chunks 0..NBIN1-1  ||  prep (Wcb = bf16(W2@W1)) -----
__global__ __launch_bounds__(512) void k1_kernel(const int* __restrict__ src,
                                                 const int* __restrict__ dst,
                                                 unsigned* __restrict__ off,
                                                 unsigned* __restrict__ grec,
                                                 const float* __restrict__ W1,
                                                 const float* __restrict__ W2,
                                                 unsigned short* __restrict__ Wcb) {
    if (blockIdx.x < NBIN1) {
        bin_chunk(src, dst, off, grec, blockIdx.x);
        return;
    }
    int t = threadIdx.x;
    for (int idx = t; idx < H2_DIM * IN_DIM; idx += 512) {
        int j = idx >> 7, f = idx & 127;
        float acc = 0.f;
        for (int k = 0; k < H1_DIM; ++k)
            acc += W2[j * H1_DIM + k] * W1[k * IN_DIM + f];
        Wcb[idx] = f2b(acc);
    }
}

// ---------------- K2: bin chunks NBIN1..NCH-1  ||  gemmy (y = x@Wc^T, MFMA) ---
__global__ __launch_bounds__(512) void k2_kernel(const int* __restrict__ src,
                                                 const int* __restrict__ dst,
                                                 unsigned* __restrict__ off,
                                                 unsigned* __restrict__ grec,
                                                 const float* __restrict__ x,
                                                 const unsigned short* __restrict__ Wcb,
                                                 unsigned short* __restrict__ yb) {
    if (blockIdx.x < NBIN2) {
        bin_chunk(src, dst, off, grec, NBIN1 + blockIdx.x);
        return;
    }
    int gb = blockIdx.x - NBIN2;
    int t = threadIdx.x;
    int w = t >> 6, l = t & 63;
    int row = l & 15, kg = l >> 4;          // kg in 0..3
    int base = gb * 128 + w * 16;
    int node = base + row;
    int nclamp = (node < N_NODES) ? node : (N_NODES - 1);
    const float* xp = x + (size_t)nclamp * IN_DIM + kg * 8;
    const unsigned short* b0p = Wcb + (size_t)row * IN_DIM + kg * 8;
    const unsigned short* b1p = Wcb + (size_t)(16 + row) * IN_DIM + kg * 8;
    f32x4 acc0 = {0.f, 0.f, 0.f, 0.f}, acc1 = {0.f, 0.f, 0.f, 0.f};
#pragma unroll
    for (int kk = 0; kk < 4; ++kk) {
        float4 xa = *(const float4*)(xp + kk * 32);
        float4 xb = *(const float4*)(xp + kk * 32 + 4);
        short8 a;
        a[0] = f2bs(xa.x); a[1] = f2bs(xa.y); a[2] = f2bs(xa.z); a[3] = f2bs(xa.w);
        a[4] = f2bs(xb.x); a[5] = f2bs(xb.y); a[6] = f2bs(xb.z); a[7] = f2bs(xb.w);
        short8 b0 = *(const short8*)(b0p + kk * 32);
        short8 b1 = *(const short8*)(b1p + kk * 32);
        acc0 = __builtin_amdgcn_mfma_f32_16x16x32_bf16(a, b0, acc0, 0, 0, 0);
        acc1 = __builtin_amdgcn_mfma_f32_16x16x32_bf16(a, b1, acc1, 0, 0, 0);
    }
#pragma unroll
    for (int r = 0; r < 4; ++r) {
        int n2 = base + kg * 4 + r;
        if (n2 < N_NODES) {
            yb[(size_t)n2 * H2_DIM + row]      = f2b(acc0[r]);
            yb[(size_t)n2 * H2_DIM + 16 + row] = f2b(acc1[r]);
        }
    }
}

// ---------------- agg: 512 thr, 32x 16-lane groups, 2x uint4 in flight --------
// Lane in group: chunk=L&3 (features 8c..8c+7, 16B), subset=L>>2 (record e+subset).
// Per node-iter: 8 records (2 quads in flight); shfl_xor(4,8) folds subsets.
// NO fused epilogue: device-scope __threadfence per block costs ~60ns L2-flush
// each on non-coherent XCD L2s (r9/r10: +90us). Separate final_kernel instead.
template <int ROUND>
__global__ __launch_bounds__(512) void agg_kernel(const unsigned short* __restrict__ in,
                                                  const unsigned* __restrict__ off,
                                                  const unsigned* __restrict__ grec,
                                                  unsigned* __restrict__ grec2,
                                                  unsigned* __restrict__ noff,
                                                  unsigned short* __restrict__ z1b,
                                                  const float* __restrict__ W2,
                                                  const float* __restrict__ b1,
                                                  const float* __restrict__ b2,
                                                  unsigned* __restrict__ pk) {
    __shared__ int len[NCH], pos[NCH], sst[NCH];
    __shared__ int shist[64], scur2[64];
    __shared__ int sscan[65];
    __shared__ unsigned rbuf[CAP2];
    __shared__ unsigned sbuf[CAP2];
    __shared__ float smq[32][4][8];
    __shared__ float scv[32], sb2v[32];
    __shared__ int s_cnt;
    int t = threadIdx.x;
    int b = blockIdx.x;
    int gid = t >> 4;              // 32 groups of 16 lanes
    int L = t & 15;
    int chunk = L & 3, subset = L >> 2;

    if (ROUND == 1) {
        if (t < NCH) {   // region table (one thread per chunk)
            unsigned o0 = off[(size_t)t * OFFW + b];
            unsigned o1 = off[(size_t)t * OFFW + b + 1];
            sst[t] = (int)o0;
            len[t] = (int)(o1 - o0);
            pos[t] = (int)(o1 - o0);
        }
        __syncthreads();
        for (int o = 1; o < NCH; o <<= 1) {
            int a = (t < NCH && t >= o) ? pos[t - o] : 0;
            __syncthreads();
            if (t < NCH) pos[t] += a;
            __syncthreads();
        }
        if (t < NCH) pos[t] -= len[t];      // exclusive
        if (t == NCH - 1) s_cnt = min(pos[t] + len[t], CAP2);
        __syncthreads();
        for (int c = gid; c < NCH; c += 32) {
            int Ln = len[c], P = pos[c], S = sst[c];
            for (int k = L; k < Ln; k += 16) {
                int q = P + k;
                if (q < CAP2) rbuf[q] = grec[(size_t)c * CH_E + S + k];
            }
        }
        if (t < 64) shist[t] = 0;
        __syncthreads();
        int cnt = s_cnt;
        for (int i = t; i < cnt; i += 512) atomicAdd(&shist[rbuf[i] >> 17], 1);
        __syncthreads();
        if (t < 64) scur2[t] = shist[t];
        __syncthreads();
        for (int o = 1; o < 64; o <<= 1) {
            int a = (t < 64 && t >= o) ? scur2[t - o] : 0;
            __syncthreads();
            if (t < 64) scur2[t] += a;
            __syncthreads();
        }
        if (t < 64) sscan[t] = scur2[t] - shist[t];
        if (t == 63) sscan[64] = scur2[63];
        __syncthreads();
        if (t < 64) scur2[t] = sscan[t];
        __syncthreads();
        for (int i = t; i < cnt; i += 512) {
            unsigned r = rbuf[i];
            int p = atomicAdd(&scur2[r >> 17], 1);
            if (p < CAP2) sbuf[p] = r;
        }
        __syncthreads();
        for (int i = t; i < cnt; i += 512) grec2[(size_t)b * CAP2 + i] = sbuf[i];
        if (t < 65) noff[(size_t)b * 65 + t] = (unsigned)sscan[t];
    } else {
        if (t < 65) sscan[t] = (int)noff[(size_t)b * 65 + t];
        __syncthreads();
        int cnt = sscan[64];
        for (int i = t; i < cnt; i += 512) sbuf[i] = grec2[(size_t)b * CAP2 + i];
        if (t < 32) {                  // inline cvec = W2 @ b1
            float s = 0.f;
            for (int k = 0; k < H1_DIM; ++k) s += W2[t * H1_DIM + k] * b1[k];
            scv[t] = s;
            sb2v[t] = b2[t];
        }
    }
    __syncthreads();

    float cfv[8], bbv[8], m[8];
    if (ROUND == 2) {
#pragma unroll
        for (int j = 0; j < 8; ++j) {
            cfv[j] = scv[chunk * 8 + j];
            bbv[j] = sb2v[chunk * 8 + j];
            m[j] = -3.402823466e+38f;
        }
    }

    for (int sl = gid; sl < NPB; sl += 32) {
        int r0 = sscan[sl], r1 = sscan[sl + 1];
        float a[8] = {0.f, 0.f, 0.f, 0.f, 0.f, 0.f, 0.f, 0.f};
        float aa[8] = {0.f, 0.f, 0.f, 0.f, 0.f, 0.f, 0.f, 0.f};
        for (int e = r0; e < r1; e += 8) {
            int eA = e + subset, eB = e + 4 + subset;
            if (eA < r1) {
                unsigned rc = sbuf[eA];
                uint4 v = *(const uint4*)(in + (size_t)(rc & 0x1FFFFu) * H2_DIM + chunk * 8);
                acc8(a, v);
            }
            if (eB < r1) {
                unsigned rc = sbuf[eB];
                uint4 v = *(const uint4*)(in + (size_t)(rc & 0x1FFFFu) * H2_DIM + chunk * 8);
                acc8(aa, v);
            }
        }
#pragma unroll
        for (int j = 0; j < 8; ++j) {
            float s = a[j] + aa[j];
            s += __shfl_xor(s, 4);
            s += __shfl_xor(s, 8);
            a[j] = s;
        }
        int node = b * NPB + sl;
        if (node < N_NODES) {
            if (ROUND == 1) {
                if (subset == 0) {
                    uint4 o;
                    o.x = (unsigned)f2b(a[0]) | ((unsigned)f2b(a[1]) << 16);
                    o.y = (unsigned)f2b(a[2]) | ((unsigned)f2b(a[3]) << 16);
                    o.z = (unsigned)f2b(a[4]) | ((unsigned)f2b(a[5]) << 16);
                    o.w = (unsigned)f2b(a[6]) | ((unsigned)f2b(a[7]) << 16);
                    *(uint4*)(z1b + (size_t)node * H2_DIM + chunk * 8) = o;
                }
            } else {
                float dg = (float)(r1 - r0);
#pragma unroll
                for (int j = 0; j < 8; ++j)
                    m[j] = fmaxf(m[j], a[j] + dg * cfv[j] + bbv[j]);
            }
        }
    }
    if (ROUND == 2) {
        if (subset == 0) {
#pragma unroll
            for (int j = 0; j < 8; ++j) smq[gid][chunk][j] = m[j];
        }
        __syncthreads();
        if (t < 32) {                  // feature f == t
            int c = t >> 3, j = t & 7;
            float mm = smq[0][c][j];
#pragma unroll
            for (int k = 1; k < 32; ++k) mm = fmaxf(mm, smq[k][c][j]);
            atomicMax(&pk[t], f32_to_key(mm));
        }
    }
}

// ---------------- out = pooled @ Wf^T + bf ----------------
__global__ void final_kernel(const unsigned* __restrict__ pk,
                             const float* __restrict__ Wf,
                             const float* __restrict__ bfv,
                             float* __restrict__ out) {
    __shared__ float pooled[H2_DIM];
    int t = threadIdx.x;
    if (t < H2_DIM) {
        unsigned k = pk[t];
        unsigned u = (k & 0x80000000u) ? (k & 0x7FFFFFFFu) : ~k;
        pooled[t] = __uint_as_float(u);
    }
    __syncthreads();
    if (t < OUT_DIM) {
        float acc = bfv[t];
        for (int j = 0; j < H2_DIM; ++j)
            acc += Wf[t * H2_DIM + j] * pooled[j];
        out[t] = acc;
    }
}

extern "C" void kernel_launch(void* const* d_in, const int* in_sizes, int n_in,
                              void* d_out, int out_size, void* d_ws, size_t ws_size,
                              hipStream_t stream) {
    const float* x  = (const float*)d_in[0];
    const int*   ei = (const int*)d_in[1];           // [2, E]: row0 = src, row1 = dst
    const float* W1 = (const float*)d_in[2];
    const float* b1 = (const float*)d_in[3];
    const float* W2 = (const float*)d_in[4];
    const float* b2 = (const float*)d_in[5];
    const float* Wf = (const float*)d_in[6];
    const float* bf = (const float*)d_in[7];
    float* out = (float*)d_out;

    const int* src = ei;
    const int* dst = ei + N_EDGES;

    // workspace carve-up (~32 MB)
    unsigned short* yb  = (unsigned short*)d_ws;                 // N*32 bf16
    unsigned short* z1b = yb + (size_t)N_NODES * H2_DIM;         // N*32 bf16
    unsigned short* Wcb = z1b + (size_t)N_NODES * H2_DIM;        // 32*128 bf16
    unsigned* pk    = (unsigned*)(Wcb + H2_DIM * IN_DIM);        // 32
    unsigned* off   = pk + H2_DIM;                               // NCH*OFFW
    unsigned* grec  = off + (size_t)NCH * OFFW;                  // N_EDGES
    unsigned* grec2 = grec + N_EDGES;                            // KB*CAP2
    unsigned* noff  = grec2 + (size_t)KB * CAP2;                 // KB*65

    hipMemsetAsync(pk, 0, H2_DIM * sizeof(unsigned), stream);

    k1_kernel<<<NBIN1 + 1, 512, 0, stream>>>(src, dst, off, grec, W1, W2, Wcb);
    k2_kernel<<<NBIN2 + NGB, 512, 0, stream>>>(src, dst, off, grec, x, Wcb, yb);

    agg_kernel<1><<<KB, 512, 0, stream>>>(yb, off, grec, grec2, noff, z1b,
                                          nullptr, nullptr, nullptr, pk);
    agg_kernel<2><<<KB, 512, 0, stream>>>(z1b, off, grec, grec2, noff, nullptr,
                                          W2, b1, b2, pk);

    final_kernel<<<1, 64, 0, stream>>>(pk, Wf, bf, out);
}

// Round 12
// 120.617 us; speedup vs baseline: 2.0277x; 1.0397x over previous
//
#include <hip/hip_runtime.h>

#define N_NODES 100000
#define N_EDGES 1600000
#define IN_DIM 128
#define H1_DIM 64
#define H2_DIM 32
#define OUT_DIM 16

#define NPB 64                       // src-nodes per bucket
#define KB 1563                      // ceil(N_NODES / NPB)
#define OFFW (KB + 1)                // off-table row width (with sentinel)
#define NCH 256                      // edge chunks (private regions)
#define CH_E (N_EDGES / NCH)         // 6250 edges per chunk (exact)
#define CAP2 1536                    // per-bucket record cap (mean 1024, +16 sigma)
#define NBIN1 64                     // bin chunks done in K1 (with prep)
#define NBIN2 (NCH - NBIN1)          // bin chunks done in K2 (with gemmy)
#define NGB 782                      // ceil(N_NODES / 128) gemmy blocks

typedef __attribute__((ext_vector_type(8))) short short8;
typedef __attribute__((ext_vector_type(4))) float f32x4;

// ---------------- helpers ----------------
__device__ inline unsigned short f2b(float v) {   // RNE f32 -> bf16
    unsigned u = __float_as_uint(v);
    u += 0x7FFF + ((u >> 16) & 1);
    return (unsigned short)(u >> 16);
}
__device__ inline short f2bs(float v) { return (short)f2b(v); }
__device__ inline unsigned f32_to_key(float v) {
    unsigned u = __float_as_uint(v);
    return (v >= 0.f) ? (u | 0x80000000u) : ~u;
}
__device__ __forceinline__ void acc8(float* a, uint4 v) {
    a[0] += __uint_as_float(v.x << 16);
    a[1] += __uint_as_float(v.x & 0xFFFF0000u);
    a[2] += __uint_as_float(v.y << 16);
    a[3] += __uint_as_float(v.y & 0xFFFF0000u);
    a[4] += __uint_as_float(v.z << 16);
    a[5] += __uint_as_float(v.z & 0xFFFF0000u);
    a[6] += __uint_as_float(v.w << 16);
    a[7] += __uint_as_float(v.w & 0xFFFF0000u);
}

// ---------------- bin chunk (shared by K1/K2): 512 threads ----------------
__device__ __forceinline__ void bin_chunk(const int* __restrict__ src,
                                          const int* __restrict__ dst,
                                          unsigned* __restrict__ off,
                                          unsigned* __restrict__ grec, int c) {
    __shared__ int hist[2048];
    __shared__ int part[512];
    __shared__ int cur[2048];
    int t = threadIdx.x;
    int e0 = c * CH_E;
    for (int i = t; i < 2048; i += 512) hist[i] = 0;
    __syncthreads();
    for (int e = t; e < CH_E; e += 512) atomicAdd(&hist[src[e0 + e] >> 6], 1);
    __syncthreads();
    int h0 = hist[4 * t], h1 = hist[4 * t + 1], h2 = hist[4 * t + 2], h3 = hist[4 * t + 3];
    int tot = h0 + h1 + h2 + h3;
    part[t] = tot;
    __syncthreads();
    for (int o = 1; o < 512; o <<= 1) {
        int a = (t >= o) ? part[t - o] : 0;
        __syncthreads();
        part[t] += a;
        __syncthreads();
    }
    int gb = part[t] - tot;
    int o0 = gb, o1 = gb + h0, o2 = o1 + h1, o3 = o2 + h2;
    int b4 = 4 * t;
    cur[b4] = o0; cur[b4 + 1] = o1; cur[b4 + 2] = o2; cur[b4 + 3] = o3;
    if (b4 + 0 < KB) off[(size_t)c * OFFW + b4 + 0] = o0;
    if (b4 + 1 < KB) off[(size_t)c * OFFW + b4 + 1] = o1;
    if (b4 + 2 < KB) off[(size_t)c * OFFW + b4 + 2] = o2;
    if (b4 + 3 < KB) off[(size_t)c * OFFW + b4 + 3] = o3;
    if (t == 0) off[(size_t)c * OFFW + KB] = CH_E;   // sentinel
    __syncthreads();
    for (int e = t; e < CH_E; e += 512) {
        int s = src[e0 + e];
        int d = dst[e0 + e];
        int p = atomicAdd(&cur[s >> 6], 1);
        grec[(size_t)e0 + p] = ((unsigned)(s & 63) << 17) | (unsigned)d;
    }
}

// ---------------- K1: bin chunks 0..NBIN1-1  ||  prep (Wcb, cvb) --------------
__global__ __launch_bounds__(512) void k1_kernel(const int* __restrict__ src,
                                                 const int* __restrict__ dst,
                                                 unsigned* __restrict__ off,
                                                 unsigned* __restrict__ grec,
                                                 const float* __restrict__ W1,
                                                 const float* __restrict__ b1,
                                                 const float* __restrict__ W2,
                                                 unsigned short* __restrict__ Wcb,
                                                 float* __restrict__ cvb) {
    if (blockIdx.x < NBIN1) {
        bin_chunk(src, dst, off, grec, blockIdx.x);
        return;
    }
    int t = threadIdx.x;
    for (int idx = t; idx < H2_DIM * IN_DIM; idx += 512) {
        int j = idx >> 7, f = idx & 127;
        float acc = 0.f;
        for (int k = 0; k < H1_DIM; ++k)
            acc += W2[j * H1_DIM + k] * W1[k * IN_DIM + f];
        Wcb[idx] = f2b(acc);
    }
    if (t < H2_DIM) {                 // cvb = W2 @ b1
        float s = 0.f;
        for (int k = 0; k < H1_DIM; ++k) s += W2[t * H1_DIM + k] * b1[k];
        cvb[t] = s;
    }
}

// ---------------- K2: bin chunks NBIN1..NCH-1  ||  gemmy (y = x@Wc^T, MFMA) ---
__global__ __launch_bounds__(512) void k2_kernel(const int* __restrict__ src,
                                                 const int* __restrict__ dst,
                                                 unsigned* __restrict__ off,
                                                 unsigned* __restrict__ grec,
                                                 const float* __restrict__ x,
                                                 const unsigned short* __restrict__ Wcb,
                                                 unsigned short* __restrict__ yb) {
    if (blockIdx.x < NBIN2) {
        bin_chunk(src, dst, off, grec, NBIN1 + blockIdx.x);
        return;
    }
    int gb = blockIdx.x - NBIN2;
    int t = threadIdx.x;
    int w = t >> 6, l = t & 63;
    int row = l & 15, kg = l >> 4;          // kg in 0..3
    int base = gb * 128 + w * 16;
    int node = base + row;
    int nclamp = (node < N_NODES) ? node : (N_NODES - 1);
    const float* xp = x + (size_t)nclamp * IN_DIM + kg * 8;
    const unsigned short* b0p = Wcb + (size_t)row * IN_DIM + kg * 8;
    const unsigned short* b1p = Wcb + (size_t)(16 + row) * IN_DIM + kg * 8;
    f32x4 acc0 = {0.f, 0.f, 0.f, 0.f}, acc1 = {0.f, 0.f, 0.f, 0.f};
#pragma unroll
    for (int kk = 0; kk < 4; ++kk) {
        float4 xa = *(const float4*)(xp + kk * 32);
        float4 xb = *(const float4*)(xp + kk * 32 + 4);
        short8 a;
        a[0] = f2bs(xa.x); a[1] = f2bs(xa.y); a[2] = f2bs(xa.z); a[3] = f2bs(xa.w);
        a[4] = f2bs(xb.x); a[5] = f2bs(xb.y); a[6] = f2bs(xb.z); a[7] = f2bs(xb.w);
        short8 b0 = *(const short8*)(b0p + kk * 32);
        short8 b1 = *(const short8*)(b1p + kk * 32);
        acc0 = __builtin_amdgcn_mfma_f32_16x16x32_bf16(a, b0, acc0, 0, 0, 0);
        acc1 = __builtin_amdgcn_mfma_f32_16x16x32_bf16(a, b1, acc1, 0, 0, 0);
    }
#pragma unroll
    for (int r = 0; r < 4; ++r) {
        int n2 = base + kg * 4 + r;
        if (n2 < N_NODES) {
            yb[(size_t)n2 * H2_DIM + row]      = f2b(acc0[r]);
            yb[(size_t)n2 * H2_DIM + 16 + row] = f2b(acc1[r]);
        }
    }
}

// ---------------- agg1: sort (binary-search copy) + gather y -> z1 ------------
__global__ __launch_bounds__(512) void agg1_kernel(const unsigned short* __restrict__ in,
                                                   const unsigned* __restrict__ off,
                                                   const unsigned* __restrict__ grec,
                                                   unsigned* __restrict__ grec2,
                                                   unsigned* __restrict__ noff,
                                                   unsigned short* __restrict__ z1b) {
    __shared__ int pos[NCH + 1], sst[NCH], len[NCH];
    __shared__ int shist[64], scur2[64];
    __shared__ int sscan[65];
    __shared__ unsigned rbuf[CAP2];
    __shared__ unsigned sbuf[CAP2];
    __shared__ int s_cnt;
    int t = threadIdx.x;
    int b = blockIdx.x;
    int gid = t >> 4;              // 32 groups of 16 lanes
    int L = t & 15;
    int chunk = L & 3, subset = L >> 2;

    if (t < NCH) {   // region table (one thread per chunk)
        unsigned o0 = off[(size_t)t * OFFW + b];
        unsigned o1 = off[(size_t)t * OFFW + b + 1];
        sst[t] = (int)o0;
        len[t] = (int)(o1 - o0);
        pos[t] = (int)(o1 - o0);
    }
    __syncthreads();
    for (int o = 1; o < NCH; o <<= 1) {
        int a = (t < NCH && t >= o) ? pos[t - o] : 0;
        __syncthreads();
        if (t < NCH) pos[t] += a;
        __syncthreads();
    }
    if (t < NCH) pos[t] -= len[t];      // exclusive
    if (t == NCH - 1) {
        pos[NCH] = pos[t] + len[t];
        s_cnt = min(pos[t] + len[t], CAP2);
    }
    __syncthreads();
    int cnt = s_cnt;
    // flat copy: binary search which chunk-run record i belongs to
    for (int i = t; i < cnt; i += 512) {
        int lo = 0, hi = NCH;          // pos[lo] <= i < pos[hi]
#pragma unroll
        for (int s = 0; s < 8; ++s) {
            int mid = (lo + hi) >> 1;
            if (pos[mid] <= i) lo = mid; else hi = mid;
        }
        rbuf[i] = grec[(size_t)lo * CH_E + sst[lo] + (i - pos[lo])];
    }
    if (t < 64) shist[t] = 0;
    __syncthreads();
    for (int i = t; i < cnt; i += 512) atomicAdd(&shist[rbuf[i] >> 17], 1);
    __syncthreads();
    if (t < 64) scur2[t] = shist[t];
    __syncthreads();
    for (int o = 1; o < 64; o <<= 1) {
        int a = (t < 64 && t >= o) ? scur2[t - o] : 0;
        __syncthreads();
        if (t < 64) scur2[t] += a;
        __syncthreads();
    }
    if (t < 64) sscan[t] = scur2[t] - shist[t];
    if (t == 63) sscan[64] = scur2[63];
    __syncthreads();
    if (t < 64) scur2[t] = sscan[t];
    __syncthreads();
    for (int i = t; i < cnt; i += 512) {
        unsigned r = rbuf[i];
        int p = atomicAdd(&scur2[r >> 17], 1);
        if (p < CAP2) sbuf[p] = r;
    }
    __syncthreads();
    for (int i = t; i < cnt; i += 512) grec2[(size_t)b * CAP2 + i] = sbuf[i];
    if (t < 65) noff[(size_t)b * 65 + t] = (unsigned)sscan[t];
    __syncthreads();

    // gather y -> z1 (32 groups x 2 nodes, 2-quad ILP, shfl_xor(4,8) fold)
    for (int sl = gid; sl < NPB; sl += 32) {
        int r0 = sscan[sl], r1 = sscan[sl + 1];
        float a[8] = {0.f, 0.f, 0.f, 0.f, 0.f, 0.f, 0.f, 0.f};
        float aa[8] = {0.f, 0.f, 0.f, 0.f, 0.f, 0.f, 0.f, 0.f};
        for (int e = r0; e < r1; e += 8) {
            int eA = e + subset, eB = e + 4 + subset;
            if (eA < r1) {
                unsigned rc = sbuf[eA];
                uint4 v = *(const uint4*)(in + (size_t)(rc & 0x1FFFFu) * H2_DIM + chunk * 8);
                acc8(a, v);
            }
            if (eB < r1) {
                unsigned rc = sbuf[eB];
                uint4 v = *(const uint4*)(in + (size_t)(rc & 0x1FFFFu) * H2_DIM + chunk * 8);
                acc8(aa, v);
            }
        }
#pragma unroll
        for (int j = 0; j < 8; ++j) {
            float s = a[j] + aa[j];
            s += __shfl_xor(s, 4);
            s += __shfl_xor(s, 8);
            a[j] = s;
        }
        int node = b * NPB + sl;
        if (node < N_NODES && subset == 0) {
            uint4 o;
            o.x = (unsigned)f2b(a[0]) | ((unsigned)f2b(a[1]) << 16);
            o.y = (unsigned)f2b(a[2]) | ((unsigned)f2b(a[3]) << 16);
            o.z = (unsigned)f2b(a[4]) | ((unsigned)f2b(a[5]) << 16);
            o.w = (unsigned)f2b(a[6]) | ((unsigned)f2b(a[7]) << 16);
            *(uint4*)(z1b + (size_t)node * H2_DIM + chunk * 8) = o;
        }
    }
}

// ---------------- agg2: barrier-free gather z1 + fused max-pool ---------------
// 1024 thr = 64 groups x 1 node. Records read DIRECTLY from grec2 (sorted,
// contiguous, L1/L2-hot); offsets from noff; cvec from cvb. No staging barriers.
__global__ __launch_bounds__(1024) void agg2_kernel(const unsigned short* __restrict__ in,
                                                    const unsigned* __restrict__ grec2,
                                                    const unsigned* __restrict__ noff,
                                                    const float* __restrict__ cvb,
                                                    const float* __restrict__ b2,
                                                    unsigned* __restrict__ pk) {
    __shared__ float smq[64][4][8];
    int t = threadIdx.x;
    int b = blockIdx.x;
    int gid = t >> 4;              // 64 groups of 16 lanes; node = b*64+gid
    int L = t & 15;
    int chunk = L & 3, subset = L >> 2;

    int r0 = (int)noff[(size_t)b * 65 + gid];
    int r1 = (int)noff[(size_t)b * 65 + gid + 1];
    const unsigned* rp = grec2 + (size_t)b * CAP2;

    float a[8] = {0.f, 0.f, 0.f, 0.f, 0.f, 0.f, 0.f, 0.f};
    float aa[8] = {0.f, 0.f, 0.f, 0.f, 0.f, 0.f, 0.f, 0.f};
    for (int e = r0; e < r1; e += 8) {
        int eA = e + subset, eB = e + 4 + subset;
        if (eA < r1) {
            unsigned rc = rp[eA];
            uint4 v = *(const uint4*)(in + (size_t)(rc & 0x1FFFFu) * H2_DIM + chunk * 8);
            acc8(a, v);
        }
        if (eB < r1) {
            unsigned rc = rp[eB];
            uint4 v = *(const uint4*)(in + (size_t)(rc & 0x1FFFFu) * H2_DIM + chunk * 8);
            acc8(aa, v);
        }
    }
#pragma unroll
    for (int j = 0; j < 8; ++j) {
        float s = a[j] + aa[j];
        s += __shfl_xor(s, 4);
        s += __shfl_xor(s, 8);
        a[j] = s;
    }

    int node = b * NPB + gid;
    float m[8];
    float dg = (float)(r1 - r0);
#pragma unroll
    for (int j = 0; j < 8; ++j) {
        float v = a[j] + dg * cvb[chunk * 8 + j] + b2[chunk * 8 + j];
        m[j] = (node < N_NODES) ? v : -3.402823466e+38f;
    }
    if (subset == 0) {
#pragma unroll
        for (int j = 0; j < 8; ++j) smq[gid][chunk][j] = m[j];
    }
    __syncthreads();
    if (t < 32) {                  // feature f == t
        int c = t >> 3, j = t & 7;
        float mm = smq[0][c][j];
#pragma unroll
        for (int k = 1; k < 64; ++k) mm = fmaxf(mm, smq[k][c][j]);
        atomicMax(&pk[t], f32_to_key(mm));
    }
}

// ---------------- out = pooled @ Wf^T + bf ----------------
__global__ void final_kernel(const unsigned* __restrict__ pk,
                             const float* __restrict__ Wf,
                             const float* __restrict__ bfv,
                             float* __restrict__ out) {
    __shared__ float pooled[H2_DIM];
    int t = threadIdx.x;
    if (t < H2_DIM) {
        unsigned k = pk[t];
        unsigned u = (k & 0x80000000u) ? (k & 0x7FFFFFFFu) : ~k;
        pooled[t] = __uint_as_float(u);
    }
    __syncthreads();
    if (t < OUT_DIM) {
        float acc = bfv[t];
        for (int j = 0; j < H2_DIM; ++j)
            acc += Wf[t * H2_DIM + j] * pooled[j];
        out[t] = acc;
    }
}

extern "C" void kernel_launch(void* const* d_in, const int* in_sizes, int n_in,
                              void* d_out, int out_size, void* d_ws, size_t ws_size,
                              hipStream_t stream) {
    const float* x  = (const float*)d_in[0];
    const int*   ei = (const int*)d_in[1];           // [2, E]: row0 = src, row1 = dst
    const float* W1 = (const float*)d_in[2];
    const float* b1 = (const float*)d_in[3];
    const float* W2 = (const float*)d_in[4];
    const float* b2 = (const float*)d_in[5];
    const float* Wf = (const float*)d_in[6];
    const float* bf = (const float*)d_in[7];
    float* out = (float*)d_out;

    const int* src = ei;
    const int* dst = ei + N_EDGES;

    // workspace carve-up (~32 MB)
    unsigned short* yb  = (unsigned short*)d_ws;                 // N*32 bf16
    unsigned short* z1b = yb + (size_t)N_NODES * H2_DIM;         // N*32 bf16
    unsigned short* Wcb = z1b + (size_t)N_NODES * H2_DIM;        // 32*128 bf16
    float* cvb      = (float*)(Wcb + H2_DIM * IN_DIM);           // 32
    unsigned* pk    = (unsigned*)(cvb + H2_DIM);                 // 32
    unsigned* off   = pk + H2_DIM;                               // NCH*OFFW
    unsigned* grec  = off + (size_t)NCH * OFFW;                  // N_EDGES
    unsigned* grec2 = grec + N_EDGES;                            // KB*CAP2
    unsigned* noff  = grec2 + (size_t)KB * CAP2;                 // KB*65

    hipMemsetAsync(pk, 0, H2_DIM * sizeof(unsigned), stream);

    k1_kernel<<<NBIN1 + 1, 512, 0, stream>>>(src, dst, off, grec, W1, b1, W2, Wcb, cvb);
    k2_kernel<<<NBIN2 + NGB, 512, 0, stream>>>(src, dst, off, grec, x, Wcb, yb);

    agg1_kernel<<<KB, 512, 0, stream>>>(yb, off, grec, grec2, noff, z1b);
    agg2_kernel<<<KB, 1024, 0, stream>>>(z1b, grec2, noff, cvb, b2, pk);

    final_kernel<<<1, 64, 0, stream>>>(pk, Wf, bf, out);
}